// Round 11
// baseline (323.748 us; speedup 1.0000x reference)
//
#include <hip/hip_runtime.h>
#include <math.h>

#define BB 8
#define PP 100
#define QQ 10000
#define NCH 157
#define MASK25 0x1555555555555ULL

__device__ __forceinline__ float frcp(float x) { return __builtin_amdgcn_rcpf(x); }
__device__ __forceinline__ float ftanh(float x) {
    float e2 = __expf(2.0f * x);
    return 1.0f - 2.0f * frcp(e2 + 1.0f);
}

// ---------------- K1: majority vote + count_d + 2-bit pack + per-chunk hist ----------------
// grid (157, 8) x 256. Block (0,0) zeroes accumulators (safe: ctr/acc untouched until k6).
__global__ void k1_ghat(const int* __restrict__ M, unsigned long long* __restrict__ Mpk,
                        unsigned char* __restrict__ ghat, unsigned char* __restrict__ cd,
                        int* __restrict__ histG, double* __restrict__ acc, int* __restrict__ ctr) {
    int b = blockIdx.y;
    int tid = threadIdx.x;
    if (blockIdx.x == 0 && blockIdx.y == 0) {
        if (tid < 2) acc[tid] = 0.0;
        if (tid == 2) *ctr = 0;
    }
    int qi = tid & 63, wv = tid >> 6;
    int q = blockIdx.x * 64 + qi;
    __shared__ unsigned int red[4][64];
    __shared__ int hist_lds[101];
    for (int i = tid; i < 101; i += 256) hist_lds[i] = 0;
    if (q < QQ) {
        const int* Mb = M + b * PP * QQ + q;
        int p0 = wv * 25;
        unsigned long long mp = 0ULL;
        #pragma unroll 5
        for (int i = 0; i < 25; i++) {
            unsigned long long m = (unsigned int)Mb[(p0 + i) * QQ];
            mp |= m << (2 * i);
        }
        Mpk[(size_t)(b * 4 + wv) * QQ + q] = mp;
        unsigned int c4 = 0;
        #pragma unroll
        for (int k = 0; k < 4; k++) {
            unsigned long long x = mp ^ (MASK25 * (unsigned long long)k);
            unsigned long long nx = ~x;
            unsigned long long bits = nx & (nx >> 1) & MASK25;
            c4 += (unsigned int)__popcll(bits) << (8 * k);
        }
        red[wv][qi] = c4;
    } else red[wv][qi] = 0;
    __syncthreads();
    if (wv == 0 && q < QQ) {
        unsigned int s = red[0][qi] + red[1][qi] + red[2][qi] + red[3][qi];
        int c0 = s & 255, c1 = (s >> 8) & 255, c2 = (s >> 16) & 255, c3 = (s >> 24) & 255;
        int g = 0, best = c0;
        if (c1 > best) { g = 1; best = c1; }
        if (c2 > best) { g = 2; best = c2; }
        if (c3 > best) { g = 3; best = c3; }
        ghat[b * QQ + q] = (unsigned char)g;
        cd[b * QQ + q] = (unsigned char)best;
        atomicAdd(&hist_lds[best], 1);
    }
    __syncthreads();
    for (int i = tid; i < 101; i += 256)
        histG[(b * NCH + blockIdx.x) * 101 + i] = hist_lds[i];
}

// ---------------- K4b: chunk prefix (in place) + value bases ----------------
__global__ void k4b_prefix(int* __restrict__ cpfx, int* __restrict__ valuebase) {
    int b = blockIdx.x, t = threadIdx.x;
    __shared__ int tot[101];
    if (t < 101) {
        int acc = 0;
        for (int c = 0; c < NCH; c++) {
            int idx = (b * NCH + c) * 101 + t;
            int x = cpfx[idx];
            cpfx[idx] = acc;
            acc += x;
        }
        tot[t] = acc;
    }
    __syncthreads();
    if (t == 0) {
        int run = 0;
        for (int v = 0; v < 101; v++) { int x = tot[v]; valuebase[b * 101 + v] = run; run += x; }
    }
}

// ---------------- K4c: stable rank -> bin_d ----------------
__global__ void k4c_bind(const unsigned char* __restrict__ cd, const int* __restrict__ cpfx,
                         const int* __restrict__ valuebase, unsigned char* __restrict__ bind) {
    int b = blockIdx.y, blk = blockIdx.x, t = threadIdx.x;
    int q = blk * 64 + t;
    __shared__ unsigned char cds[64];
    int v = 0;
    if (q < QQ) v = cd[b * QQ + q];
    cds[t] = (unsigned char)v;
    __syncthreads();
    if (q < QQ) {
        int intra = 0;
        for (int j = 0; j < t; j++) intra += (cds[j] == v);
        int rank = valuebase[b * 101 + v] + cpfx[(b * NCH + blk) * 101 + v] + intra;
        bind[b * QQ + q] = (unsigned char)(rank / 2000);
    }
}

// ---------------- K2: count_a + a_k counts + first-layer worker partial pa ----------------
__global__ void k2_counts(const unsigned long long* __restrict__ Mpk, const unsigned char* __restrict__ ghat,
                          const unsigned char* __restrict__ bind, int* __restrict__ count_a,
                          float* __restrict__ pa, const float* __restrict__ cW1) {
    int blk = blockIdx.x;
    int b = blk / PP, p = blk - b * PP;
    int t = threadIdx.x;
    int chunk = p / 25, sh = 2 * (p % 25);
    const unsigned long long* Mc = Mpk + (size_t)(b * 4 + chunk) * QQ;
    const unsigned char* gh = ghat + b * QQ;
    const unsigned char* bd = bind + b * QQ;
    int cnt = 0, k0 = 0, k1 = 0, k2 = 0, k3 = 0, k4 = 0;
    for (int q = t; q < QQ; q += 256) {
        int m = (int)((Mc[q] >> sh) & 3ULL);
        int mc = (m == (int)gh[q]);
        int bb = bd[q];
        cnt += mc;
        k0 += mc & (bb == 0); k1 += mc & (bb == 1); k2 += mc & (bb == 2);
        k3 += mc & (bb == 3); k4 += mc & (bb == 4);
    }
    __shared__ int red[4][6];
    int w = t >> 6, l = t & 63;
    int v[6] = {cnt, k0, k1, k2, k3, k4};
    #pragma unroll
    for (int i = 0; i < 6; i++) {
        int x = v[i];
        #pragma unroll
        for (int off = 32; off > 0; off >>= 1) x += __shfl_down(x, off);
        if (l == 0) red[w][i] = x;
    }
    __syncthreads();
    if (t == 0) {
        int s[6];
        #pragma unroll
        for (int i = 0; i < 6; i++) s[i] = red[0][i] + red[1][i] + red[2][i] + red[3][i];
        count_a[b * PP + p] = s[0];
        float fa0 = (float)s[0] / 10000.0f;
        float fk[5];
        #pragma unroll
        for (int k = 0; k < 5; k++) fk[k] = (float)s[1 + k] / 2000.0f;
        float* par = pa + (b * PP + p) * 12;
        #pragma unroll
        for (int j = 0; j < 10; j++) {
            float sj = fa0 * cW1[j];
            #pragma unroll
            for (int k = 0; k < 5; k++) sj = fmaf(fk[k], cW1[(1 + k) * 10 + j], sj);
            par[j] = sj;
        }
        par[10] = 0.f; par[11] = 0.f;
    }
}

// ---------------- K3: bin_a stable rank + per-bin bitmasks ----------------
__global__ void k3_bina(const int* __restrict__ count_a, unsigned long long* __restrict__ binmask) {
    int b = blockIdx.x, p = threadIdx.x;
    __shared__ int ca[PP];
    __shared__ unsigned char bn[PP];
    if (p < PP) ca[p] = count_a[b * PP + p];
    __syncthreads();
    if (p < PP) {
        int me = ca[p], r = 0;
        for (int pp = 0; pp < PP; pp++) {
            int cc = ca[pp];
            r += (cc < me) || (cc == me && pp < p);
        }
        bn[p] = (unsigned char)(r / 20);
    }
    __syncthreads();
    if (p == 0) {
        unsigned long long bm[4][5];
        #pragma unroll
        for (int c = 0; c < 4; c++)
            #pragma unroll
            for (int k = 0; k < 5; k++) bm[c][k] = 0ULL;
        for (int pp = 0; pp < PP; pp++) bm[pp / 25][bn[pp]] |= 1ULL << (2 * (pp % 25));
        for (int c = 0; c < 4; c++)
            for (int k = 0; k < 5; k++) binmask[(b * 4 + c) * 5 + k] = bm[c][k];
    }
}

// ---------------- K6: FUSED cor-MLP (phase A, r4-proven) + ref-MLP (phase B) + finalize ----------------
// grid (157, 8) x 256. Y staged in LDS (f32), never touches HBM.
__launch_bounds__(256)
__global__ void k6_fused(const unsigned long long* __restrict__ Mpk, const int* __restrict__ G_true,
    const unsigned char* __restrict__ ghat, const unsigned char* __restrict__ cd,
    const float* __restrict__ pa_g, const unsigned long long* __restrict__ binmask,
    const float* __restrict__ cW1, const float* __restrict__ cb1,
    const float* __restrict__ cW2, const float* __restrict__ cb2,
    const float* __restrict__ cW3, const float* __restrict__ cb3,
    const float* __restrict__ cW4, const float* __restrict__ cb4,
    const float* __restrict__ rW1, const float* __restrict__ rb1,
    const float* __restrict__ rW2, const float* __restrict__ rb2,
    const float* __restrict__ rW3, const float* __restrict__ rb3,
    const float* __restrict__ rW4, const float* __restrict__ rb4,
    double* __restrict__ acc, int* __restrict__ ctr, float* __restrict__ out)
{
    int b = blockIdx.y;
    int tid = threadIdx.x;
    int qi = tid & 63, wv = tid >> 6;
    int q = blockIdx.x * 64 + qi;

    __shared__ float Y_s[PP][64];                  // 25.6 KB, f32
    __shared__ unsigned long long cls_s[64][4];    // 2 KB
    __shared__ float w3_s[10][12], w1d_s[6][12], cb1_s[12];
    __shared__ float pd_s[64][11];
    __shared__ unsigned long long bm_s[4][5];
    __shared__ float rw2_s[15][16], rw3_s[15][16];
    __shared__ float rw4_s[16], rb1_s[16], rb2_s[16], rb3_s[16];
    __shared__ float wred[4][2];

    for (int i = tid; i < 120; i += 256) { int r = i / 12, c = i % 12;
        w3_s[r][c] = (c < 10) ? cW3[r * 10 + c] : 0.f; }
    for (int i = tid; i < 72; i += 256) { int r = i / 12, c = i % 12;
        w1d_s[r][c] = (c < 10) ? cW1[60 + r * 10 + c] : 0.f; }
    for (int i = tid; i < 240; i += 256) { int r = i >> 4, c = i & 15;
        rw2_s[r][c] = (c < 15) ? rW2[r * 15 + c] : 0.f;
        rw3_s[r][c] = (c < 15) ? rW3[r * 15 + c] : 0.f; }
    if (tid < 16) rw4_s[tid] = (tid < 15) ? rW4[tid] : 0.f;
    else if (tid < 32) { int j = tid - 16; rb1_s[j] = (j < 15) ? rb1[j] : 0.f; }
    else if (tid < 48) { int j = tid - 32; rb2_s[j] = (j < 15) ? rb2[j] : 0.f; }
    else if (tid < 64) { int j = tid - 48; rb3_s[j] = (j < 15) ? rb3[j] : 0.f; }
    if (tid >= 128 && tid < 140) { int j = tid - 128; cb1_s[j] = (j < 10) ? cb1[j] : 0.f; }
    if (tid >= 160 && tid < 180) { int j = tid - 160; bm_s[j / 5][j % 5] = binmask[(b * 4 + j / 5) * 5 + j % 5]; }
    __syncthreads();

    // ---- pd (wave 0) ----
    if (wv == 0 && q < QQ) {
        int g = (int)ghat[b * QQ + q];
        unsigned long long rep = MASK25 * (unsigned long long)g;
        int dc[5] = {0, 0, 0, 0, 0};
        #pragma unroll
        for (int c = 0; c < 4; c++) {
            unsigned long long mm = Mpk[(size_t)(b * 4 + c) * QQ + q];
            unsigned long long nx = ~(mm ^ rep);
            unsigned long long bits = nx & (nx >> 1) & MASK25;
            #pragma unroll
            for (int k = 0; k < 5; k++) dc[k] += __popcll(bits & bm_s[c][k]);
        }
        float dlist = (float)cd[b * QQ + q] * 0.01f;
        float dkv[5];
        #pragma unroll
        for (int k = 0; k < 5; k++) dkv[k] = dc[k] * 0.05f;
        #pragma unroll
        for (int j = 0; j < 10; j++) {
            float s = cb1_s[j];
            s = fmaf(dlist, w1d_s[0][j], s);
            #pragma unroll
            for (int k = 0; k < 5; k++) s = fmaf(dkv[k], w1d_s[1 + k][j], s);
            pd_s[qi][j] = s;
        }
    }
    __syncthreads();

    // ---- phase A: cor-MLP (r4-proven structure), Y -> LDS ----
    float lc = 0.f;
    if (q < QQ) {
        float pd[10];
        #pragma unroll
        for (int j = 0; j < 10; j++) pd[j] = pd_s[qi][j];
        unsigned long long mrun = Mpk[(size_t)(b * 4 + wv) * QQ + q];
        cls_s[qi][wv] = mrun;
        int gt = G_true[b * QQ + q];
        int p0 = wv * 25;
        const float* paB = pa_g + (size_t)b * PP * 12;
        float b4v = cb4[0];

        #pragma unroll 1
        for (int iq = 0; iq < 6; iq++) {
            int pA = p0 + iq * 4;
            float ha[4][10], hb[4][10];
            #pragma unroll
            for (int x = 0; x < 4; x++) {
                const float* par = paB + (pA + x) * 12;
                #pragma unroll
                for (int j = 0; j < 10; j++) ha[x][j] = fmaxf(par[j] + pd[j], 0.f);
            }
            #pragma unroll
            for (int x = 0; x < 4; x++)
                #pragma unroll
                for (int j = 0; j < 10; j++) hb[x][j] = cb2[j];
            #pragma unroll
            for (int j1 = 0; j1 < 10; j1++) {
                #pragma unroll
                for (int j2 = 0; j2 < 10; j2++) {
                    float w = cW2[j1 * 10 + j2];
                    hb[0][j2] = fmaf(ha[0][j1], w, hb[0][j2]);
                    hb[1][j2] = fmaf(ha[1][j1], w, hb[1][j2]);
                    hb[2][j2] = fmaf(ha[2][j1], w, hb[2][j2]);
                    hb[3][j2] = fmaf(ha[3][j1], w, hb[3][j2]);
                }
            }
            #pragma unroll
            for (int x = 0; x < 4; x++)
                #pragma unroll
                for (int j = 0; j < 10; j++) { hb[x][j] = fmaxf(hb[x][j], 0.f); ha[x][j] = cb3[j]; }
            #pragma unroll
            for (int j1 = 0; j1 < 10; j1++) {
                float wrow[12];
                const float4* wr = (const float4*)w3_s[j1];
                ((float4*)wrow)[0] = wr[0]; ((float4*)wrow)[1] = wr[1]; ((float4*)wrow)[2] = wr[2];
                #pragma unroll
                for (int j2 = 0; j2 < 10; j2++) {
                    float w = wrow[j2];
                    ha[0][j2] = fmaf(hb[0][j1], w, ha[0][j2]);
                    ha[1][j2] = fmaf(hb[1][j1], w, ha[1][j2]);
                    ha[2][j2] = fmaf(hb[2][j1], w, ha[2][j2]);
                    ha[3][j2] = fmaf(hb[3][j1], w, ha[3][j2]);
                }
            }
            #pragma unroll
            for (int x = 0; x < 4; x++) {
                float xx = b4v;
                #pragma unroll
                for (int j = 0; j < 10; j++) xx = fmaf(fmaxf(ha[x][j], 0.f), cW4[j], xx);
                float e = __expf(-xx);
                float Y = frcp(1.0f + e);
                float L = __logf(1.0f + e);          // -log(sigmoid(xx))
                Y_s[pA + x][qi] = Y;
                int m = (int)(mrun & 3ULL); mrun >>= 2;
                lc -= L + ((m == gt) ? 0.f : xx);
            }
        }
        { // 25th worker
            int pA = p0 + 24;
            const float* par = paB + pA * 12;
            float h1[10], h2[10];
            #pragma unroll
            for (int j = 0; j < 10; j++) { h1[j] = fmaxf(par[j] + pd[j], 0.f); h2[j] = cb2[j]; }
            #pragma unroll
            for (int j1 = 0; j1 < 10; j1++) {
                float x = h1[j1];
                #pragma unroll
                for (int j2 = 0; j2 < 10; j2++) h2[j2] = fmaf(x, cW2[j1 * 10 + j2], h2[j2]);
            }
            float h3[10];
            #pragma unroll
            for (int j = 0; j < 10; j++) { h2[j] = fmaxf(h2[j], 0.f); h3[j] = cb3[j]; }
            #pragma unroll
            for (int j1 = 0; j1 < 10; j1++) {
                float x = h2[j1];
                #pragma unroll
                for (int j2 = 0; j2 < 10; j2++) h3[j2] = fmaf(x, w3_s[j1][j2], h3[j2]);
            }
            float xx = b4v;
            #pragma unroll
            for (int j = 0; j < 10; j++) xx = fmaf(fmaxf(h3[j], 0.f), cW4[j], xx);
            float e = __expf(-xx);
            float Y = frcp(1.0f + e);
            float L = __logf(1.0f + e);
            Y_s[pA][qi] = Y;
            int m = (int)(mrun & 3ULL);
            lc -= L + ((m == gt) ? 0.f : xx);
        }
    }
    __syncthreads();

    // ---- phase B: ref-MLP per (q, class) ----
    int t2 = tid & 3, q2 = tid >> 2;               // q2: 0..63, t2: class
    int qq = blockIdx.x * 64 + q2;
    float lrv = 0.f;
    if (qq < QQ) {
        int gt2 = G_true[b * QQ + qq];
        float a0[15];
        #pragma unroll
        for (int j = 0; j < 15; j++) a0[j] = rb1_s[j];
        float wc[15];
        #pragma unroll
        for (int j = 0; j < 15; j++) wc[j] = rW1[j];   // row 0 (uniform -> s_load)
        #pragma unroll 1
        for (int c = 0; c < 4; c++) {
            unsigned long long mm = cls_s[q2][c];
            #pragma unroll 1
            for (int i = 0; i < 25; i++) {
                int p = c * 25 + i;
                int pn = (p + 1 < PP) ? (p + 1) : 0;
                const float* wnp = rW1 + pn * 15;
                float wn[15];
                #pragma unroll
                for (int j = 0; j < 15; j++) wn[j] = wnp[j];   // prefetch next row
                float y = Y_s[p][q2];
                int m = (int)(mm & 3ULL); mm >>= 2;
                float u = (m == t2) ? y : (1.0f - y) * (1.0f / 3.0f);
                #pragma unroll
                for (int j = 0; j < 15; j++) a0[j] = fmaf(u, wc[j], a0[j]);
                #pragma unroll
                for (int j = 0; j < 15; j++) wc[j] = wn[j];
            }
        }

        float g1[15], g2[15];
        #pragma unroll
        for (int j = 0; j < 15; j++) { g1[j] = ftanh(a0[j]); g2[j] = rb2_s[j]; }
        #pragma unroll
        for (int j1 = 0; j1 < 15; j1++) {
            float wrow[16];
            const float4* wr = (const float4*)rw2_s[j1];
            ((float4*)wrow)[0] = wr[0]; ((float4*)wrow)[1] = wr[1];
            ((float4*)wrow)[2] = wr[2]; ((float4*)wrow)[3] = wr[3];
            float x = g1[j1];
            #pragma unroll
            for (int j2 = 0; j2 < 15; j2++) g2[j2] = fmaf(x, wrow[j2], g2[j2]);
        }
        #pragma unroll
        for (int j = 0; j < 15; j++) { g2[j] = ftanh(g2[j]); g1[j] = rb3_s[j]; }
        #pragma unroll
        for (int j1 = 0; j1 < 15; j1++) {
            float wrow[16];
            const float4* wr = (const float4*)rw3_s[j1];
            ((float4*)wrow)[0] = wr[0]; ((float4*)wrow)[1] = wr[1];
            ((float4*)wrow)[2] = wr[2]; ((float4*)wrow)[3] = wr[3];
            float x = g2[j1];
            #pragma unroll
            for (int j2 = 0; j2 < 15; j2++) g1[j2] = fmaf(x, wrow[j2], g1[j2]);
        }
        float z = rb4[0];
        #pragma unroll
        for (int j = 0; j < 15; j++) z = fmaf(ftanh(g1[j]), rw4_s[j], z);

        // double softmax across the 4 class-lanes
        float zm = fmaxf(z, __shfl_xor(z, 1)); zm = fmaxf(zm, __shfl_xor(zm, 2));
        float ez = __expf(z - zm);
        float es = ez + __shfl_xor(ez, 1); es += __shfl_xor(es, 2);
        float prob = ez * frcp(es);
        float pm = fmaxf(prob, __shfl_xor(prob, 1)); pm = fmaxf(pm, __shfl_xor(pm, 2));
        float ep = __expf(prob - pm);
        float eps_ = ep + __shfl_xor(ep, 1); eps_ += __shfl_xor(eps_, 2);
        float lp = prob - (pm + __logf(eps_));
        float sel = (t2 == gt2) ? lp : 0.f;
        sel += __shfl_xor(sel, 1); sel += __shfl_xor(sel, 2);
        if (t2 == 0) lrv = sel;
    }

    // ---- block reduce -> f64 atomics; last block finalizes ----
    float v1 = lc, v2 = lrv;
    #pragma unroll
    for (int off = 32; off > 0; off >>= 1) { v1 += __shfl_down(v1, off); v2 += __shfl_down(v2, off); }
    if ((tid & 63) == 0) { wred[tid >> 6][0] = v1; wred[tid >> 6][1] = v2; }
    __syncthreads();
    if (tid == 0) {
        float s1 = wred[0][0] + wred[1][0] + wred[2][0] + wred[3][0];
        float s2 = wred[0][1] + wred[1][1] + wred[2][1] + wred[3][1];
        atomicAdd(&acc[0], (double)s1);
        atomicAdd(&acc[1], (double)s2);
        __threadfence();
        unsigned int old = atomicAdd((unsigned int*)ctr, 1u);
        if (old == (unsigned int)(NCH * BB) - 1u) {
            double a0d = atomicAdd(&acc[0], 0.0);
            double a1d = atomicAdd(&acc[1], 0.0);
            out[0] = (float)(-a0d / (double)(BB * PP * QQ));
            out[1] = (float)(-a1d / (double)(BB * QQ));
        }
    }
}

extern "C" void kernel_launch(void* const* d_in, const int* in_sizes, int n_in,
                              void* d_out, int out_size, void* d_ws, size_t ws_size,
                              hipStream_t stream) {
    const int*   M      = (const int*)d_in[0];
    const int*   G_true = (const int*)d_in[1];
    const float* cW1 = (const float*)d_in[2];  const float* cb1 = (const float*)d_in[3];
    const float* cW2 = (const float*)d_in[4];  const float* cb2 = (const float*)d_in[5];
    const float* cW3 = (const float*)d_in[6];  const float* cb3 = (const float*)d_in[7];
    const float* cW4 = (const float*)d_in[8];  const float* cb4 = (const float*)d_in[9];
    const float* rW1 = (const float*)d_in[10]; const float* rb1 = (const float*)d_in[11];
    const float* rW2 = (const float*)d_in[12]; const float* rb2 = (const float*)d_in[13];
    const float* rW3 = (const float*)d_in[14]; const float* rb3 = (const float*)d_in[15];
    const float* rW4 = (const float*)d_in[16]; const float* rb4 = (const float*)d_in[17];

    char* ws = (char*)d_ws;
    double* acc             = (double*)ws;                        // 16 B
    int* ctr                = (int*)(ws + 16);                    // 4 B
    float* pa               = (float*)(ws + 64);                  // 38400
    int* count_a            = (int*)(ws + 38464);                 // 3200
    unsigned char* ghat     = (unsigned char*)(ws + 41664);       // 80000
    unsigned char* cd       = (unsigned char*)(ws + 121664);      // 80000
    unsigned char* bind     = (unsigned char*)(ws + 201664);      // 80000
    unsigned long long* bmk = (unsigned long long*)(ws + 281664); // 1280
    int* cpfx               = (int*)(ws + 282944);                // 507224
    int* valuebase          = (int*)(ws + 790168);                // 3232
    unsigned long long* Mpk = (unsigned long long*)(ws + 793408); // 2,560,000

    dim3 gq(NCH, BB);
    k1_ghat<<<gq, 256, 0, stream>>>(M, Mpk, ghat, cd, cpfx, acc, ctr);
    k4b_prefix<<<BB, 128, 0, stream>>>(cpfx, valuebase);
    k4c_bind<<<gq, 64, 0, stream>>>(cd, cpfx, valuebase, bind);
    k2_counts<<<BB * PP, 256, 0, stream>>>(Mpk, ghat, bind, count_a, pa, cW1);
    k3_bina<<<BB, 128, 0, stream>>>(count_a, bmk);
    k6_fused<<<gq, 256, 0, stream>>>(Mpk, G_true, ghat, cd, pa, bmk,
        cW1, cb1, cW2, cb2, cW3, cb3, cW4, cb4,
        rW1, rb1, rW2, rb2, rW3, rb3, rW4, rb4,
        acc, ctr, (float*)d_out);
}

// Round 12
// 303.460 us; speedup vs baseline: 1.0669x; 1.0669x over previous
//
#include <hip/hip_runtime.h>
#include <math.h>

#define BB 8
#define PP 100
#define QQ 10000
#define NCH 157
#define MASK25 0x1555555555555ULL

__device__ __forceinline__ float frcp(float x) { return __builtin_amdgcn_rcpf(x); }
__device__ __forceinline__ float ftanh(float x) {
    float e2 = __expf(2.0f * x);
    return 1.0f - 2.0f * frcp(e2 + 1.0f);
}
__device__ __forceinline__ unsigned short f2bf(float f) {
    unsigned int u = __float_as_uint(f);
    u += 0x7FFF + ((u >> 16) & 1);
    return (unsigned short)(u >> 16);
}
__device__ __forceinline__ float bf2f(unsigned short s) {
    return __uint_as_float(((unsigned int)s) << 16);
}

// ---------------- K1: majority vote + count_d + 2-bit pack + per-chunk hist ----------------
__global__ void k1_ghat(const int* __restrict__ M, unsigned long long* __restrict__ Mpk,
                        unsigned char* __restrict__ ghat, unsigned char* __restrict__ cd,
                        int* __restrict__ histG, double* __restrict__ acc, int* __restrict__ ctr) {
    int b = blockIdx.y;
    int tid = threadIdx.x;
    if (blockIdx.x == 0 && blockIdx.y == 0) {
        if (tid < 2) acc[tid] = 0.0;
        if (tid == 2) *ctr = 0;
    }
    int qi = tid & 63, wv = tid >> 6;
    int q = blockIdx.x * 64 + qi;
    __shared__ unsigned int red[4][64];
    __shared__ int hist_lds[101];
    for (int i = tid; i < 101; i += 256) hist_lds[i] = 0;
    if (q < QQ) {
        const int* Mb = M + b * PP * QQ + q;
        int p0 = wv * 25;
        unsigned long long mp = 0ULL;
        #pragma unroll 5
        for (int i = 0; i < 25; i++) {
            unsigned long long m = (unsigned int)Mb[(p0 + i) * QQ];
            mp |= m << (2 * i);
        }
        Mpk[(size_t)(b * 4 + wv) * QQ + q] = mp;
        unsigned int c4 = 0;
        #pragma unroll
        for (int k = 0; k < 4; k++) {
            unsigned long long x = mp ^ (MASK25 * (unsigned long long)k);
            unsigned long long nx = ~x;
            unsigned long long bits = nx & (nx >> 1) & MASK25;
            c4 += (unsigned int)__popcll(bits) << (8 * k);
        }
        red[wv][qi] = c4;
    } else red[wv][qi] = 0;
    __syncthreads();
    if (wv == 0 && q < QQ) {
        unsigned int s = red[0][qi] + red[1][qi] + red[2][qi] + red[3][qi];
        int c0 = s & 255, c1 = (s >> 8) & 255, c2 = (s >> 16) & 255, c3 = (s >> 24) & 255;
        int g = 0, best = c0;
        if (c1 > best) { g = 1; best = c1; }
        if (c2 > best) { g = 2; best = c2; }
        if (c3 > best) { g = 3; best = c3; }
        ghat[b * QQ + q] = (unsigned char)g;
        cd[b * QQ + q] = (unsigned char)best;
        atomicAdd(&hist_lds[best], 1);
    }
    __syncthreads();
    for (int i = tid; i < 101; i += 256)
        histG[(b * NCH + blockIdx.x) * 101 + i] = hist_lds[i];
}

// ---------------- K4b: chunk prefix (in place) + value bases ----------------
__global__ void k4b_prefix(int* __restrict__ cpfx, int* __restrict__ valuebase) {
    int b = blockIdx.x, t = threadIdx.x;
    __shared__ int tot[101];
    if (t < 101) {
        int acc = 0;
        for (int c = 0; c < NCH; c++) {
            int idx = (b * NCH + c) * 101 + t;
            int x = cpfx[idx];
            cpfx[idx] = acc;
            acc += x;
        }
        tot[t] = acc;
    }
    __syncthreads();
    if (t == 0) {
        int run = 0;
        for (int v = 0; v < 101; v++) { int x = tot[v]; valuebase[b * 101 + v] = run; run += x; }
    }
}

// ---------------- K4c: stable rank -> bin_d ----------------
__global__ void k4c_bind(const unsigned char* __restrict__ cd, const int* __restrict__ cpfx,
                         const int* __restrict__ valuebase, unsigned char* __restrict__ bind) {
    int b = blockIdx.y, blk = blockIdx.x, t = threadIdx.x;
    int q = blk * 64 + t;
    __shared__ unsigned char cds[64];
    int v = 0;
    if (q < QQ) v = cd[b * QQ + q];
    cds[t] = (unsigned char)v;
    __syncthreads();
    if (q < QQ) {
        int intra = 0;
        for (int j = 0; j < t; j++) intra += (cds[j] == v);
        int rank = valuebase[b * 101 + v] + cpfx[(b * NCH + blk) * 101 + v] + intra;
        bind[b * QQ + q] = (unsigned char)(rank / 2000);
    }
}

// ---------------- K2: count_a + a_k counts + first-layer worker partial pa ----------------
__global__ void k2_counts(const unsigned long long* __restrict__ Mpk, const unsigned char* __restrict__ ghat,
                          const unsigned char* __restrict__ bind, int* __restrict__ count_a,
                          float* __restrict__ pa, const float* __restrict__ cW1) {
    int blk = blockIdx.x;
    int b = blk / PP, p = blk - b * PP;
    int t = threadIdx.x;
    int chunk = p / 25, sh = 2 * (p % 25);
    const unsigned long long* Mc = Mpk + (size_t)(b * 4 + chunk) * QQ;
    const unsigned char* gh = ghat + b * QQ;
    const unsigned char* bd = bind + b * QQ;
    int cnt = 0, k0 = 0, k1 = 0, k2 = 0, k3 = 0, k4 = 0;
    for (int q = t; q < QQ; q += 256) {
        int m = (int)((Mc[q] >> sh) & 3ULL);
        int mc = (m == (int)gh[q]);
        int bb = bd[q];
        cnt += mc;
        k0 += mc & (bb == 0); k1 += mc & (bb == 1); k2 += mc & (bb == 2);
        k3 += mc & (bb == 3); k4 += mc & (bb == 4);
    }
    __shared__ int red[4][6];
    int w = t >> 6, l = t & 63;
    int v[6] = {cnt, k0, k1, k2, k3, k4};
    #pragma unroll
    for (int i = 0; i < 6; i++) {
        int x = v[i];
        #pragma unroll
        for (int off = 32; off > 0; off >>= 1) x += __shfl_down(x, off);
        if (l == 0) red[w][i] = x;
    }
    __syncthreads();
    if (t == 0) {
        int s[6];
        #pragma unroll
        for (int i = 0; i < 6; i++) s[i] = red[0][i] + red[1][i] + red[2][i] + red[3][i];
        count_a[b * PP + p] = s[0];
        float fa0 = (float)s[0] / 10000.0f;
        float fk[5];
        #pragma unroll
        for (int k = 0; k < 5; k++) fk[k] = (float)s[1 + k] / 2000.0f;
        float* par = pa + (b * PP + p) * 12;
        #pragma unroll
        for (int j = 0; j < 10; j++) {
            float sj = fa0 * cW1[j];
            #pragma unroll
            for (int k = 0; k < 5; k++) sj = fmaf(fk[k], cW1[(1 + k) * 10 + j], sj);
            par[j] = sj;
        }
        par[10] = 0.f; par[11] = 0.f;
    }
}

// ---------------- K3: bin_a stable rank + per-bin bitmasks ----------------
__global__ void k3_bina(const int* __restrict__ count_a, unsigned long long* __restrict__ binmask) {
    int b = blockIdx.x, p = threadIdx.x;
    __shared__ int ca[PP];
    __shared__ unsigned char bn[PP];
    if (p < PP) ca[p] = count_a[b * PP + p];
    __syncthreads();
    if (p < PP) {
        int me = ca[p], r = 0;
        for (int pp = 0; pp < PP; pp++) {
            int cc = ca[pp];
            r += (cc < me) || (cc == me && pp < p);
        }
        bn[p] = (unsigned char)(r / 20);
    }
    __syncthreads();
    if (p == 0) {
        unsigned long long bm[4][5];
        #pragma unroll
        for (int c = 0; c < 4; c++)
            #pragma unroll
            for (int k = 0; k < 5; k++) bm[c][k] = 0ULL;
        for (int pp = 0; pp < PP; pp++) bm[pp / 25][bn[pp]] |= 1ULL << (2 * (pp % 25));
        for (int c = 0; c < 4; c++)
            for (int k = 0; k < 5; k++) binmask[(b * 4 + c) * 5 + k] = bm[c][k];
    }
}

// ---------------- K6: FUSED cor-MLP (2-worker passes) + ref-MLP + finalize ----------------
// grid (157, 8) x 256. Y staged in LDS as bf16. All cor-MLP weights via uniform s_load.
__launch_bounds__(256)
__global__ void k6_fused(const unsigned long long* __restrict__ Mpk, const int* __restrict__ G_true,
    const unsigned char* __restrict__ ghat, const unsigned char* __restrict__ cd,
    const float* __restrict__ pa_g, const unsigned long long* __restrict__ binmask,
    const float* __restrict__ cW1, const float* __restrict__ cb1,
    const float* __restrict__ cW2, const float* __restrict__ cb2,
    const float* __restrict__ cW3, const float* __restrict__ cb3,
    const float* __restrict__ cW4, const float* __restrict__ cb4,
    const float* __restrict__ rW1, const float* __restrict__ rb1,
    const float* __restrict__ rW2, const float* __restrict__ rb2,
    const float* __restrict__ rW3, const float* __restrict__ rb3,
    const float* __restrict__ rW4, const float* __restrict__ rb4,
    double* __restrict__ acc, int* __restrict__ ctr, float* __restrict__ out)
{
    int b = blockIdx.y;
    int tid = threadIdx.x;
    int qi = tid & 63, wv = tid >> 6;
    int q = blockIdx.x * 64 + qi;

    __shared__ unsigned short Y_su[PP][64];        // 12.8 KB, bf16
    __shared__ unsigned long long cls_s[64][4];    // 2 KB
    __shared__ float w1d_s[6][12], cb1_s[12];
    __shared__ float pd_s[64][11];
    __shared__ unsigned long long bm_s[4][5];
    __shared__ float rw2_s[15][16], rw3_s[15][16];
    __shared__ float rw4_s[16], rb1_s[16], rb2_s[16], rb3_s[16];
    __shared__ float wred[4][2];

    for (int i = tid; i < 72; i += 256) { int r = i / 12, c = i % 12;
        w1d_s[r][c] = (c < 10) ? cW1[60 + r * 10 + c] : 0.f; }
    for (int i = tid; i < 240; i += 256) { int r = i >> 4, c = i & 15;
        rw2_s[r][c] = (c < 15) ? rW2[r * 15 + c] : 0.f;
        rw3_s[r][c] = (c < 15) ? rW3[r * 15 + c] : 0.f; }
    if (tid < 16) rw4_s[tid] = (tid < 15) ? rW4[tid] : 0.f;
    else if (tid < 32) { int j = tid - 16; rb1_s[j] = (j < 15) ? rb1[j] : 0.f; }
    else if (tid < 48) { int j = tid - 32; rb2_s[j] = (j < 15) ? rb2[j] : 0.f; }
    else if (tid < 64) { int j = tid - 48; rb3_s[j] = (j < 15) ? rb3[j] : 0.f; }
    if (tid >= 128 && tid < 140) { int j = tid - 128; cb1_s[j] = (j < 10) ? cb1[j] : 0.f; }
    if (tid >= 160 && tid < 180) { int j = tid - 160; bm_s[j / 5][j % 5] = binmask[(b * 4 + j / 5) * 5 + j % 5]; }
    __syncthreads();

    // ---- pd (wave 0) ----
    if (wv == 0 && q < QQ) {
        int g = (int)ghat[b * QQ + q];
        unsigned long long rep = MASK25 * (unsigned long long)g;
        int dc[5] = {0, 0, 0, 0, 0};
        #pragma unroll
        for (int c = 0; c < 4; c++) {
            unsigned long long mm = Mpk[(size_t)(b * 4 + c) * QQ + q];
            unsigned long long nx = ~(mm ^ rep);
            unsigned long long bits = nx & (nx >> 1) & MASK25;
            #pragma unroll
            for (int k = 0; k < 5; k++) dc[k] += __popcll(bits & bm_s[c][k]);
        }
        float dlist = (float)cd[b * QQ + q] * 0.01f;
        float dkv[5];
        #pragma unroll
        for (int k = 0; k < 5; k++) dkv[k] = dc[k] * 0.05f;
        #pragma unroll
        for (int j = 0; j < 10; j++) {
            float s = cb1_s[j];
            s = fmaf(dlist, w1d_s[0][j], s);
            #pragma unroll
            for (int k = 0; k < 5; k++) s = fmaf(dkv[k], w1d_s[1 + k][j], s);
            pd_s[qi][j] = s;
        }
    }
    __syncthreads();

    // ---- phase A: cor-MLP, 2 workers per pass, weights via uniform s_load ----
    float lc = 0.f;
    if (q < QQ) {
        float pd[10];
        #pragma unroll
        for (int j = 0; j < 10; j++) pd[j] = pd_s[qi][j];
        unsigned long long mrun = Mpk[(size_t)(b * 4 + wv) * QQ + q];
        cls_s[qi][wv] = mrun;
        int gt = G_true[b * QQ + q];
        int p0 = wv * 25;
        const float* paB = pa_g + (size_t)b * PP * 12;
        float b4v = cb4[0];

        #pragma unroll 1
        for (int iq = 0; iq < 12; iq++) {
            int pA = p0 + iq * 2;
            const float* parA = paB + pA * 12;
            float ha[2][10], hb[2][10];
            #pragma unroll
            for (int j = 0; j < 10; j++) {
                ha[0][j] = fmaxf(parA[j] + pd[j], 0.f);
                ha[1][j] = fmaxf(parA[12 + j] + pd[j], 0.f);
                hb[0][j] = cb2[j]; hb[1][j] = cb2[j];
            }
            #pragma unroll
            for (int j1 = 0; j1 < 10; j1++) {
                float xa = ha[0][j1], xb = ha[1][j1];
                #pragma unroll
                for (int j2 = 0; j2 < 10; j2++) {
                    float w = cW2[j1 * 10 + j2];
                    hb[0][j2] = fmaf(xa, w, hb[0][j2]);
                    hb[1][j2] = fmaf(xb, w, hb[1][j2]);
                }
            }
            #pragma unroll
            for (int j = 0; j < 10; j++) {
                hb[0][j] = fmaxf(hb[0][j], 0.f); hb[1][j] = fmaxf(hb[1][j], 0.f);
                ha[0][j] = cb3[j]; ha[1][j] = cb3[j];
            }
            #pragma unroll
            for (int j1 = 0; j1 < 10; j1++) {
                float xa = hb[0][j1], xb = hb[1][j1];
                #pragma unroll
                for (int j2 = 0; j2 < 10; j2++) {
                    float w = cW3[j1 * 10 + j2];
                    ha[0][j2] = fmaf(xa, w, ha[0][j2]);
                    ha[1][j2] = fmaf(xb, w, ha[1][j2]);
                }
            }
            #pragma unroll
            for (int x = 0; x < 2; x++) {
                float xx = b4v;
                #pragma unroll
                for (int j = 0; j < 10; j++) xx = fmaf(fmaxf(ha[x][j], 0.f), cW4[j], xx);
                float e = __expf(-xx);
                float Y = frcp(1.0f + e);
                float L = __logf(1.0f + e);          // -log(sigmoid(xx))
                Y_su[pA + x][qi] = f2bf(Y);
                int m = (int)(mrun & 3ULL); mrun >>= 2;
                lc -= L + ((m == gt) ? 0.f : xx);
            }
        }
        { // 25th worker
            int pA = p0 + 24;
            const float* par = paB + pA * 12;
            float h1[10], h2[10];
            #pragma unroll
            for (int j = 0; j < 10; j++) { h1[j] = fmaxf(par[j] + pd[j], 0.f); h2[j] = cb2[j]; }
            #pragma unroll
            for (int j1 = 0; j1 < 10; j1++) {
                float x = h1[j1];
                #pragma unroll
                for (int j2 = 0; j2 < 10; j2++) h2[j2] = fmaf(x, cW2[j1 * 10 + j2], h2[j2]);
            }
            float h3[10];
            #pragma unroll
            for (int j = 0; j < 10; j++) { h2[j] = fmaxf(h2[j], 0.f); h3[j] = cb3[j]; }
            #pragma unroll
            for (int j1 = 0; j1 < 10; j1++) {
                float x = h2[j1];
                #pragma unroll
                for (int j2 = 0; j2 < 10; j2++) h3[j2] = fmaf(x, cW3[j1 * 10 + j2], h3[j2]);
            }
            float xx = b4v;
            #pragma unroll
            for (int j = 0; j < 10; j++) xx = fmaf(fmaxf(h3[j], 0.f), cW4[j], xx);
            float e = __expf(-xx);
            float Y = frcp(1.0f + e);
            float L = __logf(1.0f + e);
            Y_su[pA][qi] = f2bf(Y);
            int m = (int)(mrun & 3ULL);
            lc -= L + ((m == gt) ? 0.f : xx);
        }
    }
    __syncthreads();

    // ---- phase B: ref-MLP per (q, class); rW1 rows direct uniform s_load ----
    int t2 = tid & 3, q2 = tid >> 2;
    int qq = blockIdx.x * 64 + q2;
    float lrv = 0.f;
    if (qq < QQ) {
        int gt2 = G_true[b * QQ + qq];
        float a0[15];
        #pragma unroll
        for (int j = 0; j < 15; j++) a0[j] = rb1_s[j];
        #pragma unroll 1
        for (int c = 0; c < 4; c++) {
            unsigned long long mm = cls_s[q2][c];
            #pragma unroll 5
            for (int i = 0; i < 25; i++) {
                int p = c * 25 + i;
                const float* wr = rW1 + p * 15;
                float y = bf2f(Y_su[p][q2]);
                int m = (int)((mm >> (2 * i)) & 3ULL);
                float u = (m == t2) ? y : (1.0f - y) * (1.0f / 3.0f);
                #pragma unroll
                for (int j = 0; j < 15; j++) a0[j] = fmaf(u, wr[j], a0[j]);
            }
        }

        float g1[15], g2[15];
        #pragma unroll
        for (int j = 0; j < 15; j++) { g1[j] = ftanh(a0[j]); g2[j] = rb2_s[j]; }
        #pragma unroll
        for (int j1 = 0; j1 < 15; j1++) {
            float wrow[16];
            const float4* wr = (const float4*)rw2_s[j1];
            ((float4*)wrow)[0] = wr[0]; ((float4*)wrow)[1] = wr[1];
            ((float4*)wrow)[2] = wr[2]; ((float4*)wrow)[3] = wr[3];
            float x = g1[j1];
            #pragma unroll
            for (int j2 = 0; j2 < 15; j2++) g2[j2] = fmaf(x, wrow[j2], g2[j2]);
        }
        #pragma unroll
        for (int j = 0; j < 15; j++) { g2[j] = ftanh(g2[j]); g1[j] = rb3_s[j]; }
        #pragma unroll
        for (int j1 = 0; j1 < 15; j1++) {
            float wrow[16];
            const float4* wr = (const float4*)rw3_s[j1];
            ((float4*)wrow)[0] = wr[0]; ((float4*)wrow)[1] = wr[1];
            ((float4*)wrow)[2] = wr[2]; ((float4*)wrow)[3] = wr[3];
            float x = g2[j1];
            #pragma unroll
            for (int j2 = 0; j2 < 15; j2++) g1[j2] = fmaf(x, wrow[j2], g1[j2]);
        }
        float z = rb4[0];
        #pragma unroll
        for (int j = 0; j < 15; j++) z = fmaf(ftanh(g1[j]), rw4_s[j], z);

        // double softmax across the 4 class-lanes
        float zm = fmaxf(z, __shfl_xor(z, 1)); zm = fmaxf(zm, __shfl_xor(zm, 2));
        float ez = __expf(z - zm);
        float es = ez + __shfl_xor(ez, 1); es += __shfl_xor(es, 2);
        float prob = ez * frcp(es);
        float pm = fmaxf(prob, __shfl_xor(prob, 1)); pm = fmaxf(pm, __shfl_xor(pm, 2));
        float ep = __expf(prob - pm);
        float eps_ = ep + __shfl_xor(ep, 1); eps_ += __shfl_xor(eps_, 2);
        float lp = prob - (pm + __logf(eps_));
        float sel = (t2 == gt2) ? lp : 0.f;
        sel += __shfl_xor(sel, 1); sel += __shfl_xor(sel, 2);
        if (t2 == 0) lrv = sel;
    }

    // ---- block reduce -> f64 atomics; last block finalizes ----
    float v1 = lc, v2 = lrv;
    #pragma unroll
    for (int off = 32; off > 0; off >>= 1) { v1 += __shfl_down(v1, off); v2 += __shfl_down(v2, off); }
    if ((tid & 63) == 0) { wred[tid >> 6][0] = v1; wred[tid >> 6][1] = v2; }
    __syncthreads();
    if (tid == 0) {
        float s1 = wred[0][0] + wred[1][0] + wred[2][0] + wred[3][0];
        float s2 = wred[0][1] + wred[1][1] + wred[2][1] + wred[3][1];
        atomicAdd(&acc[0], (double)s1);
        atomicAdd(&acc[1], (double)s2);
        __threadfence();
        unsigned int old = atomicAdd((unsigned int*)ctr, 1u);
        if (old == (unsigned int)(NCH * BB) - 1u) {
            double a0d = atomicAdd(&acc[0], 0.0);
            double a1d = atomicAdd(&acc[1], 0.0);
            out[0] = (float)(-a0d / (double)(BB * PP * QQ));
            out[1] = (float)(-a1d / (double)(BB * QQ));
        }
    }
}

extern "C" void kernel_launch(void* const* d_in, const int* in_sizes, int n_in,
                              void* d_out, int out_size, void* d_ws, size_t ws_size,
                              hipStream_t stream) {
    const int*   M      = (const int*)d_in[0];
    const int*   G_true = (const int*)d_in[1];
    const float* cW1 = (const float*)d_in[2];  const float* cb1 = (const float*)d_in[3];
    const float* cW2 = (const float*)d_in[4];  const float* cb2 = (const float*)d_in[5];
    const float* cW3 = (const float*)d_in[6];  const float* cb3 = (const float*)d_in[7];
    const float* cW4 = (const float*)d_in[8];  const float* cb4 = (const float*)d_in[9];
    const float* rW1 = (const float*)d_in[10]; const float* rb1 = (const float*)d_in[11];
    const float* rW2 = (const float*)d_in[12]; const float* rb2 = (const float*)d_in[13];
    const float* rW3 = (const float*)d_in[14]; const float* rb3 = (const float*)d_in[15];
    const float* rW4 = (const float*)d_in[16]; const float* rb4 = (const float*)d_in[17];

    char* ws = (char*)d_ws;
    double* acc             = (double*)ws;                        // 16 B
    int* ctr                = (int*)(ws + 16);                    // 4 B
    float* pa               = (float*)(ws + 64);                  // 38400
    int* count_a            = (int*)(ws + 38464);                 // 3200
    unsigned char* ghat     = (unsigned char*)(ws + 41664);       // 80000
    unsigned char* cd       = (unsigned char*)(ws + 121664);      // 80000
    unsigned char* bind     = (unsigned char*)(ws + 201664);      // 80000
    unsigned long long* bmk = (unsigned long long*)(ws + 281664); // 1280
    int* cpfx               = (int*)(ws + 282944);                // 507224
    int* valuebase          = (int*)(ws + 790168);                // 3232
    unsigned long long* Mpk = (unsigned long long*)(ws + 793408); // 2,560,000

    dim3 gq(NCH, BB);
    k1_ghat<<<gq, 256, 0, stream>>>(M, Mpk, ghat, cd, cpfx, acc, ctr);
    k4b_prefix<<<BB, 128, 0, stream>>>(cpfx, valuebase);
    k4c_bind<<<gq, 64, 0, stream>>>(cd, cpfx, valuebase, bind);
    k2_counts<<<BB * PP, 256, 0, stream>>>(Mpk, ghat, bind, count_a, pa, cW1);
    k3_bina<<<BB, 128, 0, stream>>>(count_a, bmk);
    k6_fused<<<gq, 256, 0, stream>>>(Mpk, G_true, ghat, cd, pa, bmk,
        cW1, cb1, cW2, cb2, cW3, cb3, cW4, cb4,
        rW1, rb1, rW2, rb2, rW3, rb3, rW4, rb4,
        acc, ctr, (float*)d_out);
}